// Round 5
// baseline (144.125 us; speedup 1.0000x reference)
//
#include <hip/hip_runtime.h>

// GENConv softmax-aggregation + MLP for MI355X (gfx950) — round 16.
//
// R15 post-mortem: dword gather + balanced ranks -6.5us (matched). agg ~21us,
// partition ~8us, rest = ~92us harness poison fills (own roofline) + gaps.
// R16: qword gather, 8-lane groups. Lane owns a channel QUAD (uint2 8B load);
// 8 lanes cover 32 ch; 32 groups own ONE rank-adjacent pair each (kp loop
// gone). Per-thread iters 8.8 -> ~4.7, gather VMEM insts halved, loop
// overhead halved, LDS entry reads halved; in-flight depth kept at 8 loads.
// Risk: accum 16 + in-flight 16 VGPRs -> ~60-64 total, at the (256,8) cap.
// Wave w gets contiguous ranks 16w..16w+15: light waves finish early and
// free issue slots for the 7 other resident blocks.
//
// Math (passed r1-r15): msg = bf16(relu(x)+eps) bounded -> skip segment-max;
//   h[n,c] = sum exp(b*m)*m / sum exp(b*m);  out = relu(h@W1+b1)@W2+b2

#define N_NODES 100000
#define N_EDGES 1600000
#define DCH 32
#define HCH 64
#define EPS 1e-7f

#define NPB 256                       // nodes per coarse bucket (dst >> 8)
#define NB 391                        // ceil(100000/256)
#define CAPB 4544                     // mean 4092, +7 sigma
#define GSTRIDE 16
#define P1_BLOCKS 512
#define P1_THREADS 512
#define CHUNK 3125                    // 512 * 3125 = 1.6M exactly
#define SLOT 48                       // per-node LDS bin cap (P[Poi16>48]~1e-11)
#define SENT_OFF (N_NODES * 64u)      // byte offset of sentinel msg row

typedef __attribute__((ext_vector_type(8))) short bf16x8;
typedef __attribute__((ext_vector_type(4))) float f32x4;

__device__ inline unsigned short f2b(float v) {   // fp32 -> bf16 RNE
    unsigned u = __float_as_uint(v);
    return (unsigned short)((u + 0x7FFFu + ((u >> 16) & 1u)) >> 16);
}

// ---------------------------------------------------------------------------
// Pass 1: bf16 msg table (+ sentinel row) + weight frags + coarse-bucket
// partition via DIRECT scatter. dst chunk cached in LDS (read once).
// Entry packing: bits 0-23 = src*64 (byte offset of msg row), bits 24-31 =
// dst&255 (local node; bits 30-31 = quarter).
// ---------------------------------------------------------------------------
__global__ __launch_bounds__(P1_THREADS) void genconv_partition(
    const float* __restrict__ x,
    const int* __restrict__ eidx,     // [2E]: [0,E)=dst, [E,2E)=src
    const float* __restrict__ W1, const float* __restrict__ W2,
    int* __restrict__ gcnt,           // [NB*GSTRIDE] zeroed; bucket totals
    unsigned* __restrict__ buf,       // [NB*CAPB] packed entries
    unsigned short* __restrict__ msgb,
    unsigned short* __restrict__ W1f, unsigned short* __restrict__ W2f)
{
    __shared__ int hcnt[512];
    __shared__ int hcur[512];
    __shared__ int dstc[CHUNK];       // 12.5 KB dst cache

    const int tid = threadIdx.x;

    // --- fused bf16 msg table: grid-stride float4 over x (800k float4) ---
    {
        const int nthreads = P1_BLOCKS * P1_THREADS;
        for (int q4 = blockIdx.x * P1_THREADS + tid; q4 < N_NODES * DCH / 4;
             q4 += nthreads) {
            float4 v = ((const float4*)x)[q4];
            ushort4 o;
            o.x = f2b(fmaxf(v.x, 0.0f) + EPS);
            o.y = f2b(fmaxf(v.y, 0.0f) + EPS);
            o.z = f2b(fmaxf(v.z, 0.0f) + EPS);
            o.w = f2b(fmaxf(v.w, 0.0f) + EPS);
            ((ushort4*)msgb)[q4] = o;
        }
    }
    // --- fused weight-frag prep + sentinel row (block 0) ---
    if (blockIdx.x == 0 && tid < 256) {
        {   // W1 [32,64]: col-tile f
            int f = tid >> 6, lane = tid & 63;
            int col = lane & 15, quad = lane >> 4;
#pragma unroll
            for (int j = 0; j < 8; ++j) {
                int k = quad * 8 + j;
                W1f[(f * 64 + lane) * 8 + j] = f2b(W1[k * HCH + f * 16 + col]);
            }
        }
        {   // W2 [64,32]: n = col tile, kk = k half
            int n = tid >> 7, kk = (tid >> 6) & 1, lane = tid & 63;
            int col = lane & 15, quad = lane >> 4;
#pragma unroll
            for (int j = 0; j < 8; ++j) {
                int k = kk * 32 + quad * 8 + j;
                W2f[((n * 2 + kk) * 64 + lane) * 8 + j] = f2b(W2[k * DCH + n * 16 + col]);
            }
        }
        // sentinel msg row: m = -3.39e38 -> w = exp2(-inf) = +0, w*m = +-0
        if (tid < DCH) msgb[N_NODES * DCH + tid] = 0xFF7Fu;
    }

    const int start = blockIdx.x * CHUNK;
    const int end = min(start + CHUNK, N_EDGES);
    const int n = end - start;

    hcnt[tid] = 0;
    __syncthreads();

    // load dst chunk into LDS once; histogram from LDS
    for (int j = tid; j < n; j += P1_THREADS) {
        int d = eidx[start + j];
        dstc[j] = d;
        atomicAdd(&hcnt[d >> 8], 1);
    }
    __syncthreads();

    // reserve global space per bucket; cursor = global base within region
    if (tid < NB) {
        int c = hcnt[tid];
        hcur[tid] = (c > 0) ? atomicAdd(&gcnt[tid * GSTRIDE], c) : 0;
    }
    __syncthreads();

    // direct scatter: ~8-entry runs per (block,bucket); L2 merges writebacks
    for (int j = tid; j < n; j += P1_THREADS) {
        int dst = dstc[j];
        int src = eidx[N_EDGES + start + j];
        int b = dst >> 8;
        int p = atomicAdd(&hcur[b], 1);
        if (p < CAPB)
            buf[(unsigned)b * CAPB + (unsigned)p] =
                ((unsigned)src << 6) | ((unsigned)(dst & (NPB - 1)) << 24);
    }
}

// ---------------------------------------------------------------------------
// Pass 2: block = quarter of a coarse bucket (64 nodes). Filtered scatter
// into sentinel-padded 48-slot per-node LDS bins, count-balanced branchless
// QWORD gather (8-lane group per node pair, 4 ch/lane, 8 loads in flight),
// bf16 h tile in LDS (unioned over dead bins), MFMA MLP, store.
// Grid = 4*NB = 1564; LDS 17.9KB -> 8 blocks/CU, all blocks co-resident.
// ---------------------------------------------------------------------------
__global__ __launch_bounds__(256, 8) void genconv_agg_mlp(
    const unsigned short* __restrict__ msgb,
    const int* __restrict__ gcnt,
    const unsigned* __restrict__ buf,
    const float* __restrict__ beta,
    const unsigned short* __restrict__ W1f,
    const unsigned short* __restrict__ W2f,
    const float* __restrict__ b1,
    const float* __restrict__ b2,
    float* __restrict__ out)          // [N,32]
{
    // bins (12288B, phase A: scatter+gather) unions with hid (9216B,
    // phase B: MFMA). Separated by the __syncthreads() after the gather.
    __shared__ __attribute__((aligned(16))) unsigned char pool[64 * SLOT * 4];
    unsigned* bins = (unsigned*)pool;                          // [64*SLOT]
    unsigned short* hid = (unsigned short*)pool;               // [4*16*72]
    __shared__ int hcnt[64];
    __shared__ int perm[64];                                   // rank -> node
    __shared__ __attribute__((aligned(16))) unsigned short sha[64 * 40];  // 5 KB

    // pre-fill bins with sentinel so over-read pads contribute exactly 0
    {
        uint4 sv = {SENT_OFF, SENT_OFF, SENT_OFF, SENT_OFF};
        for (int i = threadIdx.x; i < 64 * SLOT / 4; i += 256)
            ((uint4*)bins)[i] = sv;
        if (threadIdx.x < 64) hcnt[threadIdx.x] = 0;
    }
    __syncthreads();

    const int cb = blockIdx.x >> 2;            // coarse bucket 0..390
    const unsigned q = blockIdx.x & 3u;        // 64-node quarter
    const int cnt = min(gcnt[cb * GSTRIDE], CAPB);
    const unsigned* bp = buf + (size_t)cb * CAPB;

    // filtered single-pass scatter into per-node bins (pre-masked entries)
    {
        int nv = cnt & ~3;
        for (int i = threadIdx.x * 4; i < nv; i += 1024) {
            uint4 e4 = *(const uint4*)(bp + i);
#pragma unroll
            for (int u = 0; u < 4; ++u) {
                unsigned e = (u == 0) ? e4.x : (u == 1) ? e4.y : (u == 2) ? e4.z : e4.w;
                if ((e >> 30) == q) {
                    int ln = (e >> 24) & 63;
                    int p = atomicAdd(&hcnt[ln], 1);
                    if (p < SLOT) bins[ln * SLOT + p] = e & 0xFFFFFFu;
                }
            }
        }
        for (int i = nv + threadIdx.x; i < cnt; i += 256) {
            unsigned e = bp[i];
            if ((e >> 30) == q) {
                int ln = (e >> 24) & 63;
                int p = atomicAdd(&hcnt[ln], 1);
                if (p < SLOT) bins[ln * SLOT + p] = e & 0xFFFFFFu;
            }
        }
    }
    __syncthreads();

    // branch-free rank by count (desc): balanced group assignment
    if (threadIdx.x < 64) {
        int c = hcnt[threadIdx.x];
        int r = 0;
#pragma unroll 8
        for (int j = 0; j < 64; ++j) {
            int cj = hcnt[j];
            r += (cj > c) || (cj == c && j < (int)threadIdx.x);
        }
        perm[r] = threadIdx.x;
    }
    __syncthreads();

    const int lane8 = threadIdx.x & 7;     // channel quad (ch 4l..4l+3)
    const int g = threadIdx.x >> 3;        // group 0..31: one node pair
    const float bl2 = beta[0] * 1.4426950408889634f;   // beta * log2(e)
    const unsigned loff = (unsigned)lane8 * 8u;        // ch-quad byte offset
    const char* mb = (const char*)msgb;                // saddr base

    // qword dual-stream gather: 1 pair/group, 8x8B loads in flight.
    // ranks 2g,2g+1 adjacent -> pair balanced; wave w holds ranks
    // 16w..16w+15 -> small within-wave divergence spread.
    {
        int na = perm[2 * g], nc = perm[2 * g + 1];
        int ma = min(hcnt[na], SLOT);
        int mc = min(hcnt[nc], SLOT);
        int T = max((ma + 3) >> 2, (mc + 3) >> 2);
        const uint4* ba = (const uint4*)&bins[na * SLOT];
        const uint4* bc = (const uint4*)&bins[nc * SLOT];
        float sa0 = 0.f, sa1 = 0.f, sa2 = 0.f, sa3 = 0.f;
        float pa0 = 0.f, pa1 = 0.f, pa2 = 0.f, pa3 = 0.f;
        float sc0 = 0.f, sc1 = 0.f, sc2 = 0.f, sc3 = 0.f;
        float pc0 = 0.f, pc1 = 0.f, pc2 = 0.f, pc3 = 0.f;
        for (int t = 0; t < T; ++t) {
            uint4 ea = ba[t];                       // broadcast ds_read_b128
            uint4 ec = bc[t];
            uint2 A0 = *(const uint2*)(mb + (ea.x + loff));
            uint2 A1 = *(const uint2*)(mb + (ea.y + loff));
            uint2 A2 = *(const uint2*)(mb + (ea.z + loff));
            uint2 A3 = *(const uint2*)(mb + (ea.w + loff));
            uint2 C0 = *(const uint2*)(mb + (ec.x + loff));
            uint2 C1 = *(const uint2*)(mb + (ec.y + loff));
            uint2 C2 = *(const uint2*)(mb + (ec.z + loff));
            uint2 C3 = *(const uint2*)(mb + (ec.w + loff));
#define GEDGE(D, S0, S1, S2, S3, P0, P1, P2, P3)                              \
            {                                                                 \
                float v0 = __uint_as_float(D.x << 16);                        \
                float v1 = __uint_as_float(D.x & 0xFFFF0000u);                \
                float v2 = __uint_as_float(D.y << 16);                        \
                float v3 = __uint_as_float(D.y & 0xFFFF0000u);                \
                float w0 = __builtin_amdgcn_exp2f(bl2 * v0);                  \
                float w1 = __builtin_amdgcn_exp2f(bl2 * v1);                  \
                float w2 = __builtin_amdgcn_exp2f(bl2 * v2);                  \
                float w3 = __builtin_amdgcn_exp2f(bl2 * v3);                  \
                S0 += w0; P0 += w0 * v0;                                      \
                S1 += w1; P1 += w1 * v1;                                      \
                S2 += w2; P2 += w2 * v2;                                      \
                S3 += w3; P3 += w3 * v3;                                      \
            }
            GEDGE(A0, sa0, sa1, sa2, sa3, pa0, pa1, pa2, pa3)
            GEDGE(A1, sa0, sa1, sa2, sa3, pa0, pa1, pa2, pa3)
            GEDGE(A2, sa0, sa1, sa2, sa3, pa0, pa1, pa2, pa3)
            GEDGE(A3, sa0, sa1, sa2, sa3, pa0, pa1, pa2, pa3)
            GEDGE(C0, sc0, sc1, sc2, sc3, pc0, pc1, pc2, pc3)
            GEDGE(C1, sc0, sc1, sc2, sc3, pc0, pc1, pc2, pc3)
            GEDGE(C2, sc0, sc1, sc2, sc3, pc0, pc1, pc2, pc3)
            GEDGE(C3, sc0, sc1, sc2, sc3, pc0, pc1, pc2, pc3)
#undef GEDGE
        }
        float ha0 = (sa0 > 0.0f) ? (pa0 / sa0) : 0.0f;
        float ha1 = (sa1 > 0.0f) ? (pa1 / sa1) : 0.0f;
        float ha2 = (sa2 > 0.0f) ? (pa2 / sa2) : 0.0f;
        float ha3 = (sa3 > 0.0f) ? (pa3 / sa3) : 0.0f;
        float hc0 = (sc0 > 0.0f) ? (pc0 / sc0) : 0.0f;
        float hc1 = (sc1 > 0.0f) ? (pc1 / sc1) : 0.0f;
        float hc2 = (sc2 > 0.0f) ? (pc2 / sc2) : 0.0f;
        float hc3 = (sc3 > 0.0f) ? (pc3 / sc3) : 0.0f;
        uint2 wa, wc;
        wa.x = (unsigned)f2b(ha0) | ((unsigned)f2b(ha1) << 16);
        wa.y = (unsigned)f2b(ha2) | ((unsigned)f2b(ha3) << 16);
        wc.x = (unsigned)f2b(hc0) | ((unsigned)f2b(hc1) << 16);
        wc.y = (unsigned)f2b(hc2) | ((unsigned)f2b(hc3) << 16);
        // byte offsets node*80 + lane8*8: 8B-aligned ds_write_b64
        *(uint2*)&sha[na * 40 + lane8 * 4] = wa;
        *(uint2*)&sha[nc * 40 + lane8 * 4] = wc;
    }
    __syncthreads();   // bins dead from here; pool reused as hid

    // ---- MFMA MLP: wave wv owns nodes [blockIdx.x*64 + wv*16, +16) ----
    const int wv = threadIdx.x >> 6;
    const int lane = threadIdx.x & 63;
    const int col = lane & 15, quad = lane >> 4;
    const int n0 = blockIdx.x * 64 + wv * 16;

    bf16x8 a = *(const bf16x8*)&sha[(wv * 16 + col) * 40 + quad * 8];

    const bf16x8* w1p = (const bf16x8*)W1f;
    f32x4 z = {0.f, 0.f, 0.f, 0.f};
    f32x4 c0 = __builtin_amdgcn_mfma_f32_16x16x32_bf16(a, w1p[0 * 64 + lane], z, 0, 0, 0);
    f32x4 c1 = __builtin_amdgcn_mfma_f32_16x16x32_bf16(a, w1p[1 * 64 + lane], z, 0, 0, 0);
    f32x4 c2 = __builtin_amdgcn_mfma_f32_16x16x32_bf16(a, w1p[2 * 64 + lane], z, 0, 0, 0);
    f32x4 c3 = __builtin_amdgcn_mfma_f32_16x16x32_bf16(a, w1p[3 * 64 + lane], z, 0, 0, 0);

    float bb0 = b1[col], bb1 = b1[16 + col], bb2 = b1[32 + col], bb3 = b1[48 + col];
    unsigned short* hrow = &hid[wv * 16 * 72];
#pragma unroll
    for (int r = 0; r < 4; ++r) {
        int row = quad * 4 + r;
        hrow[row * 72 + col]      = f2b(fmaxf(c0[r] + bb0, 0.f));
        hrow[row * 72 + 16 + col] = f2b(fmaxf(c1[r] + bb1, 0.f));
        hrow[row * 72 + 32 + col] = f2b(fmaxf(c2[r] + bb2, 0.f));
        hrow[row * 72 + 48 + col] = f2b(fmaxf(c3[r] + bb3, 0.f));
    }
    // per-wave LDS region: in-wave ordering suffices (r7-r15 precedent)

    bf16x8 h0 = *(const bf16x8*)&hrow[col * 72 + quad * 8];        // k 0..31
    bf16x8 h1 = *(const bf16x8*)&hrow[col * 72 + 32 + quad * 8];   // k 32..63

    const bf16x8* w2p = (const bf16x8*)W2f;
    f32x4 o0 = __builtin_amdgcn_mfma_f32_16x16x32_bf16(h0, w2p[0 * 64 + lane], z, 0, 0, 0);
    o0 = __builtin_amdgcn_mfma_f32_16x16x32_bf16(h1, w2p[1 * 64 + lane], o0, 0, 0, 0);
    f32x4 o1 = __builtin_amdgcn_mfma_f32_16x16x32_bf16(h0, w2p[2 * 64 + lane], z, 0, 0, 0);
    o1 = __builtin_amdgcn_mfma_f32_16x16x32_bf16(h1, w2p[3 * 64 + lane], o1, 0, 0, 0);

    float d0 = b2[col], d1 = b2[16 + col];
#pragma unroll
    for (int r = 0; r < 4; ++r) {
        int row = n0 + quad * 4 + r;
        if (row < N_NODES) {
            out[(size_t)row * DCH + col]      = o0[r] + d0;
            out[(size_t)row * DCH + 16 + col] = o1[r] + d1;
        }
    }
}

extern "C" void kernel_launch(void* const* d_in, const int* in_sizes, int n_in,
                              void* d_out, int out_size, void* d_ws, size_t ws_size,
                              hipStream_t stream) {
    const float* x    = (const float*)d_in[0];
    const int*   eidx = (const int*)d_in[1];
    const float* beta = (const float*)d_in[2];
    const float* W1   = (const float*)d_in[3];
    const float* b1   = (const float*)d_in[4];
    const float* W2   = (const float*)d_in[5];
    const float* b2   = (const float*)d_in[6];
    float* out = (float*)d_out;

    int* gcnt = (int*)d_ws;                                        // 25 KB
    unsigned* buf = (unsigned*)(gcnt + NB * GSTRIDE);              // 7.1 MB
    unsigned short* msgb = (unsigned short*)(buf + (size_t)NB * CAPB); // 6.4 MB + sentinel
    unsigned short* W1f = msgb + (size_t)(N_NODES + 1) * DCH;      // 4 KB
    unsigned short* W2f = W1f + 4 * 64 * 8;                        // 4 KB

    hipMemsetAsync(gcnt, 0, (size_t)NB * GSTRIDE * sizeof(int), stream);

    genconv_partition<<<P1_BLOCKS, P1_THREADS, 0, stream>>>(
        x, eidx, W1, W2, gcnt, buf, msgb, W1f, W2f);
    genconv_agg_mlp<<<4 * NB, 256, 0, stream>>>(msgb, gcnt, buf, beta,
                                                W1f, W2f, b1, b2, out);
}

// Round 6
// 129.713 us; speedup vs baseline: 1.1111x; 1.1111x over previous
//
#include <hip/hip_runtime.h>

// GENConv softmax-aggregation + MLP for MI355X (gfx950) — round 17.
//
// R16 post-mortem: qword gather REGRESSED +14.6us — VGPR spill signature
// (16 accum + 16 in-flight + entries > 64-reg cap at 8 waves/EU), exactly
// the pre-registered risk. R15's 16-lane/dword shape is the right
// register/depth balance.
// R17 = exact R15 gather (dword, 16-lane groups, snake ranks) + ONE change
// that leaves per-thread registers untouched: 512-thread blocks over
// 128-node halves (grid 2*NB). Filter now reads each coarse bucket 2x
// instead of 4x (-12.8MB LLC traffic, keep-rate 1/2), per-block fixed
// costs amortized 2x, finer rank quantiles. LDS 35.8KB -> 4 blocks/CU x
// 8 waves = 32 waves/CU (same max); all 782 blocks co-resident.
//
// Math (passed r1-r16): msg = bf16(relu(x)+eps) bounded -> skip segment-max;
//   h[n,c] = sum exp(b*m)*m / sum exp(b*m);  out = relu(h@W1+b1)@W2+b2

#define N_NODES 100000
#define N_EDGES 1600000
#define DCH 32
#define HCH 64
#define EPS 1e-7f

#define NPB 256                       // nodes per coarse bucket (dst >> 8)
#define NB 391                        // ceil(100000/256)
#define CAPB 4544                     // mean 4092, +7 sigma
#define GSTRIDE 16
#define P1_BLOCKS 512
#define P1_THREADS 512
#define CHUNK 3125                    // 512 * 3125 = 1.6M exactly
#define SLOT 48                       // per-node LDS bin cap (P[Poi16>48]~1e-11)
#define SENT_OFF (N_NODES * 64u)      // byte offset of sentinel msg row
#define HNODES 128                    // nodes per agg block (half bucket)

typedef __attribute__((ext_vector_type(8))) short bf16x8;
typedef __attribute__((ext_vector_type(4))) float f32x4;

__device__ inline unsigned short f2b(float v) {   // fp32 -> bf16 RNE
    unsigned u = __float_as_uint(v);
    return (unsigned short)((u + 0x7FFFu + ((u >> 16) & 1u)) >> 16);
}

// ---------------------------------------------------------------------------
// Pass 1: bf16 msg table (+ sentinel row) + weight frags + coarse-bucket
// partition via DIRECT scatter. dst chunk cached in LDS (read once).
// Entry packing: bits 0-23 = src*64 (byte offset of msg row), bits 24-31 =
// dst&255 (local node; bit 31 = half).
// ---------------------------------------------------------------------------
__global__ __launch_bounds__(P1_THREADS) void genconv_partition(
    const float* __restrict__ x,
    const int* __restrict__ eidx,     // [2E]: [0,E)=dst, [E,2E)=src
    const float* __restrict__ W1, const float* __restrict__ W2,
    int* __restrict__ gcnt,           // [NB*GSTRIDE] zeroed; bucket totals
    unsigned* __restrict__ buf,       // [NB*CAPB] packed entries
    unsigned short* __restrict__ msgb,
    unsigned short* __restrict__ W1f, unsigned short* __restrict__ W2f)
{
    __shared__ int hcnt[512];
    __shared__ int hcur[512];
    __shared__ int dstc[CHUNK];       // 12.5 KB dst cache

    const int tid = threadIdx.x;

    // --- fused bf16 msg table: grid-stride float4 over x (800k float4) ---
    {
        const int nthreads = P1_BLOCKS * P1_THREADS;
        for (int q4 = blockIdx.x * P1_THREADS + tid; q4 < N_NODES * DCH / 4;
             q4 += nthreads) {
            float4 v = ((const float4*)x)[q4];
            ushort4 o;
            o.x = f2b(fmaxf(v.x, 0.0f) + EPS);
            o.y = f2b(fmaxf(v.y, 0.0f) + EPS);
            o.z = f2b(fmaxf(v.z, 0.0f) + EPS);
            o.w = f2b(fmaxf(v.w, 0.0f) + EPS);
            ((ushort4*)msgb)[q4] = o;
        }
    }
    // --- fused weight-frag prep + sentinel row (block 0) ---
    if (blockIdx.x == 0 && tid < 256) {
        {   // W1 [32,64]: col-tile f
            int f = tid >> 6, lane = tid & 63;
            int col = lane & 15, quad = lane >> 4;
#pragma unroll
            for (int j = 0; j < 8; ++j) {
                int k = quad * 8 + j;
                W1f[(f * 64 + lane) * 8 + j] = f2b(W1[k * HCH + f * 16 + col]);
            }
        }
        {   // W2 [64,32]: n = col tile, kk = k half
            int n = tid >> 7, kk = (tid >> 6) & 1, lane = tid & 63;
            int col = lane & 15, quad = lane >> 4;
#pragma unroll
            for (int j = 0; j < 8; ++j) {
                int k = kk * 32 + quad * 8 + j;
                W2f[((n * 2 + kk) * 64 + lane) * 8 + j] = f2b(W2[k * DCH + n * 16 + col]);
            }
        }
        // sentinel msg row: m = -3.39e38 -> w = exp2(-inf) = +0, w*m = +-0
        if (tid < DCH) msgb[N_NODES * DCH + tid] = 0xFF7Fu;
    }

    const int start = blockIdx.x * CHUNK;
    const int end = min(start + CHUNK, N_EDGES);
    const int n = end - start;

    hcnt[tid] = 0;
    __syncthreads();

    // load dst chunk into LDS once; histogram from LDS
    for (int j = tid; j < n; j += P1_THREADS) {
        int d = eidx[start + j];
        dstc[j] = d;
        atomicAdd(&hcnt[d >> 8], 1);
    }
    __syncthreads();

    // reserve global space per bucket; cursor = global base within region
    if (tid < NB) {
        int c = hcnt[tid];
        hcur[tid] = (c > 0) ? atomicAdd(&gcnt[tid * GSTRIDE], c) : 0;
    }
    __syncthreads();

    // direct scatter: ~8-entry runs per (block,bucket); L2 merges writebacks
    for (int j = tid; j < n; j += P1_THREADS) {
        int dst = dstc[j];
        int src = eidx[N_EDGES + start + j];
        int b = dst >> 8;
        int p = atomicAdd(&hcur[b], 1);
        if (p < CAPB)
            buf[(unsigned)b * CAPB + (unsigned)p] =
                ((unsigned)src << 6) | ((unsigned)(dst & (NPB - 1)) << 24);
    }
}

// ---------------------------------------------------------------------------
// Pass 2: block = HALF of a coarse bucket (128 nodes, 512 threads).
// Filtered scatter into sentinel-padded 48-slot per-node LDS bins,
// count-balanced branchless DWORD gather (16-lane group per node pair,
// 2 ch/lane, 8 loads in flight — R15's verified shape), bf16 h tile in
// LDS (unioned over dead bins), MFMA MLP (8 waves x 16 nodes), store.
// Grid = 2*NB = 782; LDS 35.8KB -> 4 blocks/CU x 8 waves = 32 waves/CU.
// ---------------------------------------------------------------------------
__global__ __launch_bounds__(512, 8) void genconv_agg_mlp(
    const unsigned short* __restrict__ msgb,
    const int* __restrict__ gcnt,
    const unsigned* __restrict__ buf,
    const float* __restrict__ beta,
    const unsigned short* __restrict__ W1f,
    const unsigned short* __restrict__ W2f,
    const float* __restrict__ b1,
    const float* __restrict__ b2,
    float* __restrict__ out)          // [N,32]
{
    // bins (24576B, phase A) unions with hid (18432B, phase B: MFMA).
    __shared__ __attribute__((aligned(16))) unsigned char pool[HNODES * SLOT * 4];
    unsigned* bins = (unsigned*)pool;                          // [128*SLOT]
    unsigned short* hid = (unsigned short*)pool;               // [8*16*72]
    __shared__ int hcnt[HNODES];
    __shared__ int perm[HNODES];                               // rank -> node
    __shared__ __attribute__((aligned(16))) unsigned short sha[HNODES * 40]; // 10 KB

    // pre-fill bins with sentinel so over-read pads contribute exactly 0
    {
        uint4 sv = {SENT_OFF, SENT_OFF, SENT_OFF, SENT_OFF};
        for (int i = threadIdx.x; i < HNODES * SLOT / 4; i += 512)
            ((uint4*)bins)[i] = sv;
        if (threadIdx.x < HNODES) hcnt[threadIdx.x] = 0;
    }
    __syncthreads();

    const int cb = blockIdx.x >> 1;            // coarse bucket 0..390
    const unsigned hf = blockIdx.x & 1u;       // 128-node half
    const int cnt = min(gcnt[cb * GSTRIDE], CAPB);
    const unsigned* bp = buf + (size_t)cb * CAPB;

    // filtered single-pass scatter into per-node bins (pre-masked entries)
    {
        int nv = cnt & ~3;
        for (int i = threadIdx.x * 4; i < nv; i += 2048) {
            uint4 e4 = *(const uint4*)(bp + i);
#pragma unroll
            for (int u = 0; u < 4; ++u) {
                unsigned e = (u == 0) ? e4.x : (u == 1) ? e4.y : (u == 2) ? e4.z : e4.w;
                if ((e >> 31) == hf) {
                    int ln = (e >> 24) & 127;
                    int p = atomicAdd(&hcnt[ln], 1);
                    if (p < SLOT) bins[ln * SLOT + p] = e & 0xFFFFFFu;
                }
            }
        }
        for (int i = nv + threadIdx.x; i < cnt; i += 512) {
            unsigned e = bp[i];
            if ((e >> 31) == hf) {
                int ln = (e >> 24) & 127;
                int p = atomicAdd(&hcnt[ln], 1);
                if (p < SLOT) bins[ln * SLOT + p] = e & 0xFFFFFFu;
            }
        }
    }
    __syncthreads();

    // branch-free rank by count (desc): balanced wave assignment
    if (threadIdx.x < HNODES) {
        int c = hcnt[threadIdx.x];
        int r = 0;
#pragma unroll 8
        for (int j = 0; j < HNODES; ++j) {
            int cj = hcnt[j];
            r += (cj > c) || (cj == c && j < (int)threadIdx.x);
        }
        perm[r] = threadIdx.x;
    }
    __syncthreads();

    const int lane16 = threadIdx.x & 15;   // channel pair index (ch 2l,2l+1)
    const int qw = threadIdx.x >> 4;       // 16-lane group 0..31
    const int wvg = qw >> 2, qi = qw & 3;  // wave id 0..7, quarter in wave
    const float bl2 = beta[0] * 1.4426950408889634f;   // beta * log2(e)
    const unsigned loff = (unsigned)lane16 * 4u;       // channel-pair byte off
    const char* mb = (const char*)msgb;                // saddr base

    // dword dual-stream gather: 2 nodes/group, 8 dwords in flight.
    // snake rank-windows: wave wvg -> windows {wvg, 15-wvg}; concurrent
    // nodes are rank-adjacent -> minimal divergence waste.
#pragma unroll
    for (int kp = 0; kp < 2; ++kp) {
        int window = kp ? (15 - wvg) : wvg;
        int s = window * 8 + qi * 2;
        int na = perm[s], nc = perm[s + 1];
        int ma = min(hcnt[na], SLOT);
        int mc = min(hcnt[nc], SLOT);
        int T = max((ma + 3) >> 2, (mc + 3) >> 2);
        const uint4* ba = (const uint4*)&bins[na * SLOT];
        const uint4* bc = (const uint4*)&bins[nc * SLOT];
        float seaL = 0.f, seaH = 0.f, smaL = 0.f, smaH = 0.f;
        float secL = 0.f, secH = 0.f, smcL = 0.f, smcH = 0.f;
        for (int t = 0; t < T; ++t) {
            uint4 ea = ba[t];                       // broadcast ds_read_b128
            uint4 ec = bc[t];
            unsigned da0 = *(const unsigned*)(mb + (ea.x + loff));
            unsigned da1 = *(const unsigned*)(mb + (ea.y + loff));
            unsigned da2 = *(const unsigned*)(mb + (ea.z + loff));
            unsigned da3 = *(const unsigned*)(mb + (ea.w + loff));
            unsigned dc0 = *(const unsigned*)(mb + (ec.x + loff));
            unsigned dc1 = *(const unsigned*)(mb + (ec.y + loff));
            unsigned dc2 = *(const unsigned*)(mb + (ec.z + loff));
            unsigned dc3 = *(const unsigned*)(mb + (ec.w + loff));
            // lo channel = bits 0-15, hi channel = bits 16-31
            float aL0 = __uint_as_float(da0 << 16), aH0 = __uint_as_float(da0 & 0xFFFF0000u);
            float aL1 = __uint_as_float(da1 << 16), aH1 = __uint_as_float(da1 & 0xFFFF0000u);
            float aL2 = __uint_as_float(da2 << 16), aH2 = __uint_as_float(da2 & 0xFFFF0000u);
            float aL3 = __uint_as_float(da3 << 16), aH3 = __uint_as_float(da3 & 0xFFFF0000u);
            float cL0 = __uint_as_float(dc0 << 16), cH0 = __uint_as_float(dc0 & 0xFFFF0000u);
            float cL1 = __uint_as_float(dc1 << 16), cH1 = __uint_as_float(dc1 & 0xFFFF0000u);
            float cL2 = __uint_as_float(dc2 << 16), cH2 = __uint_as_float(dc2 & 0xFFFF0000u);
            float cL3 = __uint_as_float(dc3 << 16), cH3 = __uint_as_float(dc3 & 0xFFFF0000u);
            float wL0 = __builtin_amdgcn_exp2f(bl2 * aL0);
            float wL1 = __builtin_amdgcn_exp2f(bl2 * aL1);
            float wL2 = __builtin_amdgcn_exp2f(bl2 * aL2);
            float wL3 = __builtin_amdgcn_exp2f(bl2 * aL3);
            float wH0 = __builtin_amdgcn_exp2f(bl2 * aH0);
            float wH1 = __builtin_amdgcn_exp2f(bl2 * aH1);
            float wH2 = __builtin_amdgcn_exp2f(bl2 * aH2);
            float wH3 = __builtin_amdgcn_exp2f(bl2 * aH3);
            float vL0 = __builtin_amdgcn_exp2f(bl2 * cL0);
            float vL1 = __builtin_amdgcn_exp2f(bl2 * cL1);
            float vL2 = __builtin_amdgcn_exp2f(bl2 * cL2);
            float vL3 = __builtin_amdgcn_exp2f(bl2 * cL3);
            float vH0 = __builtin_amdgcn_exp2f(bl2 * cH0);
            float vH1 = __builtin_amdgcn_exp2f(bl2 * cH1);
            float vH2 = __builtin_amdgcn_exp2f(bl2 * cH2);
            float vH3 = __builtin_amdgcn_exp2f(bl2 * cH3);
            seaL += (wL0 + wL1) + (wL2 + wL3);
            seaH += (wH0 + wH1) + (wH2 + wH3);
            secL += (vL0 + vL1) + (vL2 + vL3);
            secH += (vH0 + vH1) + (vH2 + vH3);
            smaL += wL0 * aL0 + wL1 * aL1 + wL2 * aL2 + wL3 * aL3;
            smaH += wH0 * aH0 + wH1 * aH1 + wH2 * aH2 + wH3 * aH3;
            smcL += vL0 * cL0 + vL1 * cL1 + vL2 * cL2 + vL3 * cL3;
            smcH += vH0 * cH0 + vH1 * cH1 + vH2 * cH2 + vH3 * cH3;
        }
        float haL = (seaL > 0.0f) ? (smaL / seaL) : 0.0f;
        float haH = (seaH > 0.0f) ? (smaH / seaH) : 0.0f;
        float hcL = (secL > 0.0f) ? (smcL / secL) : 0.0f;
        float hcH = (secH > 0.0f) ? (smcH / secH) : 0.0f;
        // packed ushort2 writes (byte offset node*80 + lane16*4, 4B aligned)
        *(unsigned*)&sha[na * 40 + lane16 * 2] =
            (unsigned)f2b(haL) | ((unsigned)f2b(haH) << 16);
        *(unsigned*)&sha[nc * 40 + lane16 * 2] =
            (unsigned)f2b(hcL) | ((unsigned)f2b(hcH) << 16);
    }
    __syncthreads();   // bins dead from here; pool reused as hid

    // ---- MFMA MLP: wave wv owns nodes [blockIdx.x*128 + wv*16, +16) ----
    const int wv = threadIdx.x >> 6;       // 0..7
    const int lane = threadIdx.x & 63;
    const int col = lane & 15, quad = lane >> 4;
    const int n0 = blockIdx.x * HNODES + wv * 16;

    bf16x8 a = *(const bf16x8*)&sha[(wv * 16 + col) * 40 + quad * 8];

    const bf16x8* w1p = (const bf16x8*)W1f;
    f32x4 z = {0.f, 0.f, 0.f, 0.f};
    f32x4 c0 = __builtin_amdgcn_mfma_f32_16x16x32_bf16(a, w1p[0 * 64 + lane], z, 0, 0, 0);
    f32x4 c1 = __builtin_amdgcn_mfma_f32_16x16x32_bf16(a, w1p[1 * 64 + lane], z, 0, 0, 0);
    f32x4 c2 = __builtin_amdgcn_mfma_f32_16x16x32_bf16(a, w1p[2 * 64 + lane], z, 0, 0, 0);
    f32x4 c3 = __builtin_amdgcn_mfma_f32_16x16x32_bf16(a, w1p[3 * 64 + lane], z, 0, 0, 0);

    float bb0 = b1[col], bb1 = b1[16 + col], bb2 = b1[32 + col], bb3 = b1[48 + col];
    unsigned short* hrow = &hid[wv * 16 * 72];
#pragma unroll
    for (int r = 0; r < 4; ++r) {
        int row = quad * 4 + r;
        hrow[row * 72 + col]      = f2b(fmaxf(c0[r] + bb0, 0.f));
        hrow[row * 72 + 16 + col] = f2b(fmaxf(c1[r] + bb1, 0.f));
        hrow[row * 72 + 32 + col] = f2b(fmaxf(c2[r] + bb2, 0.f));
        hrow[row * 72 + 48 + col] = f2b(fmaxf(c3[r] + bb3, 0.f));
    }
    // per-wave LDS region: in-wave ordering suffices (r7-r16 precedent)

    bf16x8 h0 = *(const bf16x8*)&hrow[col * 72 + quad * 8];        // k 0..31
    bf16x8 h1 = *(const bf16x8*)&hrow[col * 72 + 32 + quad * 8];   // k 32..63

    const bf16x8* w2p = (const bf16x8*)W2f;
    f32x4 o0 = __builtin_amdgcn_mfma_f32_16x16x32_bf16(h0, w2p[0 * 64 + lane], z, 0, 0, 0);
    o0 = __builtin_amdgcn_mfma_f32_16x16x32_bf16(h1, w2p[1 * 64 + lane], o0, 0, 0, 0);
    f32x4 o1 = __builtin_amdgcn_mfma_f32_16x16x32_bf16(h0, w2p[2 * 64 + lane], z, 0, 0, 0);
    o1 = __builtin_amdgcn_mfma_f32_16x16x32_bf16(h1, w2p[3 * 64 + lane], o1, 0, 0, 0);

    float d0 = b2[col], d1 = b2[16 + col];
#pragma unroll
    for (int r = 0; r < 4; ++r) {
        int row = n0 + quad * 4 + r;
        if (row < N_NODES) {
            out[(size_t)row * DCH + col]      = o0[r] + d0;
            out[(size_t)row * DCH + 16 + col] = o1[r] + d1;
        }
    }
}

extern "C" void kernel_launch(void* const* d_in, const int* in_sizes, int n_in,
                              void* d_out, int out_size, void* d_ws, size_t ws_size,
                              hipStream_t stream) {
    const float* x    = (const float*)d_in[0];
    const int*   eidx = (const int*)d_in[1];
    const float* beta = (const float*)d_in[2];
    const float* W1   = (const float*)d_in[3];
    const float* b1   = (const float*)d_in[4];
    const float* W2   = (const float*)d_in[5];
    const float* b2   = (const float*)d_in[6];
    float* out = (float*)d_out;

    int* gcnt = (int*)d_ws;                                        // 25 KB
    unsigned* buf = (unsigned*)(gcnt + NB * GSTRIDE);              // 7.1 MB
    unsigned short* msgb = (unsigned short*)(buf + (size_t)NB * CAPB); // 6.4 MB + sentinel
    unsigned short* W1f = msgb + (size_t)(N_NODES + 1) * DCH;      // 4 KB
    unsigned short* W2f = W1f + 4 * 64 * 8;                        // 4 KB

    hipMemsetAsync(gcnt, 0, (size_t)NB * GSTRIDE * sizeof(int), stream);

    genconv_partition<<<P1_BLOCKS, P1_THREADS, 0, stream>>>(
        x, eidx, W1, W2, gcnt, buf, msgb, W1f, W2f);
    genconv_agg_mlp<<<2 * NB, 512, 0, stream>>>(msgb, gcnt, buf, beta,
                                                W1f, W2f, b1, b2, out);
}

// Round 7
// 129.244 us; speedup vs baseline: 1.1151x; 1.0036x over previous
//
#include <hip/hip_runtime.h>

// GENConv softmax-aggregation + MLP for MI355X (gfx950) — round 18.
//
// R17 post-mortem: 512-thread/128-node restructure neutral (filter phase
// exonerated); R15-shape gather remains the right register/depth balance.
// Budget: ~92us harness poison fills (own roofline) + partition ~8 +
// agg ~19 + gaps. Floors: partition ~5.3us (32MB HBM), agg ~12us
// (51.2M ch-edges x (quarter-rate exp + 4 VALU)). ~10% total headroom.
// R18 (register-safe pair):
//  (a) partition int4-vectorized edge reads: CHUNK 3200 / 500 blocks
//      (500*3200 = 1.6M exact, aligned, no tails) -> 4 edges per VMEM
//      read in histogram+scatter (atomics unchanged).
//  (b) agg gather entry-prefetch: ds_read_b128 of entries[t+1] issued
//      under iteration t's 8 global loads (+8 VGPR, ~50 < 64 cap;
//      pool +16B slack keeps last prefetch in-bounds).
//
// Math (passed r1-r17): msg = bf16(relu(x)+eps) bounded -> skip segment-max;
//   h[n,c] = sum exp(b*m)*m / sum exp(b*m);  out = relu(h@W1+b1)@W2+b2

#define N_NODES 100000
#define N_EDGES 1600000
#define DCH 32
#define HCH 64
#define EPS 1e-7f

#define NPB 256                       // nodes per coarse bucket (dst >> 8)
#define NB 391                        // ceil(100000/256)
#define CAPB 4544                     // mean 4092, +7 sigma
#define GSTRIDE 16
#define P1_BLOCKS 500
#define P1_THREADS 512
#define CHUNK 3200                    // 500 * 3200 = 1.6M exactly
#define SLOT 48                       // per-node LDS bin cap (P[Poi16>48]~1e-11)
#define SENT_OFF (N_NODES * 64u)      // byte offset of sentinel msg row
#define HNODES 128                    // nodes per agg block (half bucket)

typedef __attribute__((ext_vector_type(8))) short bf16x8;
typedef __attribute__((ext_vector_type(4))) float f32x4;

__device__ inline unsigned short f2b(float v) {   // fp32 -> bf16 RNE
    unsigned u = __float_as_uint(v);
    return (unsigned short)((u + 0x7FFFu + ((u >> 16) & 1u)) >> 16);
}

// ---------------------------------------------------------------------------
// Pass 1: bf16 msg table (+ sentinel row) + weight frags + coarse-bucket
// partition via DIRECT scatter. dst chunk cached in LDS (int4 reads).
// Entry packing: bits 0-23 = src*64 (byte offset of msg row), bits 24-31 =
// dst&255 (local node; bit 31 = half).
// ---------------------------------------------------------------------------
__global__ __launch_bounds__(P1_THREADS) void genconv_partition(
    const float* __restrict__ x,
    const int* __restrict__ eidx,     // [2E]: [0,E)=dst, [E,2E)=src
    const float* __restrict__ W1, const float* __restrict__ W2,
    int* __restrict__ gcnt,           // [NB*GSTRIDE] zeroed; bucket totals
    unsigned* __restrict__ buf,       // [NB*CAPB] packed entries
    unsigned short* __restrict__ msgb,
    unsigned short* __restrict__ W1f, unsigned short* __restrict__ W2f)
{
    __shared__ int hcnt[512];
    __shared__ int hcur[512];
    __shared__ int dstc[CHUNK];       // 12.8 KB dst cache

    const int tid = threadIdx.x;

    // --- fused bf16 msg table: grid-stride float4 over x (800k float4) ---
    {
        const int nthreads = P1_BLOCKS * P1_THREADS;
        for (int q4 = blockIdx.x * P1_THREADS + tid; q4 < N_NODES * DCH / 4;
             q4 += nthreads) {
            float4 v = ((const float4*)x)[q4];
            ushort4 o;
            o.x = f2b(fmaxf(v.x, 0.0f) + EPS);
            o.y = f2b(fmaxf(v.y, 0.0f) + EPS);
            o.z = f2b(fmaxf(v.z, 0.0f) + EPS);
            o.w = f2b(fmaxf(v.w, 0.0f) + EPS);
            ((ushort4*)msgb)[q4] = o;
        }
    }
    // --- fused weight-frag prep + sentinel row (block 0) ---
    if (blockIdx.x == 0 && tid < 256) {
        {   // W1 [32,64]: col-tile f
            int f = tid >> 6, lane = tid & 63;
            int col = lane & 15, quad = lane >> 4;
#pragma unroll
            for (int j = 0; j < 8; ++j) {
                int k = quad * 8 + j;
                W1f[(f * 64 + lane) * 8 + j] = f2b(W1[k * HCH + f * 16 + col]);
            }
        }
        {   // W2 [64,32]: n = col tile, kk = k half
            int n = tid >> 7, kk = (tid >> 6) & 1, lane = tid & 63;
            int col = lane & 15, quad = lane >> 4;
#pragma unroll
            for (int j = 0; j < 8; ++j) {
                int k = kk * 32 + quad * 8 + j;
                W2f[((n * 2 + kk) * 64 + lane) * 8 + j] = f2b(W2[k * DCH + n * 16 + col]);
            }
        }
        // sentinel msg row: m = -3.39e38 -> w = exp2(-inf) = +0, w*m = +-0
        if (tid < DCH) msgb[N_NODES * DCH + tid] = 0xFF7Fu;
    }

    const int start = blockIdx.x * CHUNK;   // every block full (500*3200=1.6M)

    hcnt[tid] = 0;
    __syncthreads();

    // int4 edge reads: dst chunk -> LDS + histogram (4 edges / VMEM instr)
    for (int j = tid * 4; j < CHUNK; j += P1_THREADS * 4) {
        int4 d4 = *(const int4*)(eidx + start + j);
        *(int4*)&dstc[j] = d4;
        atomicAdd(&hcnt[d4.x >> 8], 1);
        atomicAdd(&hcnt[d4.y >> 8], 1);
        atomicAdd(&hcnt[d4.z >> 8], 1);
        atomicAdd(&hcnt[d4.w >> 8], 1);
    }
    __syncthreads();

    // reserve global space per bucket; cursor = global base within region
    if (tid < NB) {
        int c = hcnt[tid];
        hcur[tid] = (c > 0) ? atomicAdd(&gcnt[tid * GSTRIDE], c) : 0;
    }
    __syncthreads();

    // direct scatter, int4 src reads: ~8-entry runs; L2 merges writebacks
    for (int j = tid * 4; j < CHUNK; j += P1_THREADS * 4) {
        int4 s4 = *(const int4*)(eidx + N_EDGES + start + j);
        int4 d4 = *(const int4*)&dstc[j];
#pragma unroll
        for (int u = 0; u < 4; ++u) {
            int dst = (u == 0) ? d4.x : (u == 1) ? d4.y : (u == 2) ? d4.z : d4.w;
            int src = (u == 0) ? s4.x : (u == 1) ? s4.y : (u == 2) ? s4.z : s4.w;
            int b = dst >> 8;
            int p = atomicAdd(&hcur[b], 1);
            if (p < CAPB)
                buf[(unsigned)b * CAPB + (unsigned)p] =
                    ((unsigned)src << 6) | ((unsigned)(dst & (NPB - 1)) << 24);
        }
    }
}

// ---------------------------------------------------------------------------
// Pass 2: block = HALF of a coarse bucket (128 nodes, 512 threads).
// Filtered scatter into sentinel-padded 48-slot per-node LDS bins,
// count-balanced branchless DWORD gather with entry PREFETCH pipeline
// (16-lane group per node pair, 2 ch/lane, 8 global loads + 2 prefetch
// ds_reads in flight), bf16 h tile in LDS (unioned over dead bins),
// MFMA MLP (8 waves x 16 nodes), store.
// Grid = 2*NB = 782; LDS ~35.9KB -> 4 blocks/CU x 8 waves = 32 waves/CU.
// ---------------------------------------------------------------------------
__global__ __launch_bounds__(512, 8) void genconv_agg_mlp(
    const unsigned short* __restrict__ msgb,
    const int* __restrict__ gcnt,
    const unsigned* __restrict__ buf,
    const float* __restrict__ beta,
    const unsigned short* __restrict__ W1f,
    const unsigned short* __restrict__ W2f,
    const float* __restrict__ b1,
    const float* __restrict__ b2,
    float* __restrict__ out)          // [N,32]
{
    // bins (24576B + 16B prefetch slack, phase A) unions with hid (phase B).
    __shared__ __attribute__((aligned(16))) unsigned char pool[HNODES * SLOT * 4 + 16];
    unsigned* bins = (unsigned*)pool;                          // [128*SLOT]
    unsigned short* hid = (unsigned short*)pool;               // [8*16*72]
    __shared__ int hcnt[HNODES];
    __shared__ int perm[HNODES];                               // rank -> node
    __shared__ __attribute__((aligned(16))) unsigned short sha[HNODES * 40]; // 10 KB

    // pre-fill bins with sentinel so over-read pads contribute exactly 0
    {
        uint4 sv = {SENT_OFF, SENT_OFF, SENT_OFF, SENT_OFF};
        for (int i = threadIdx.x; i < HNODES * SLOT / 4 + 1; i += 512)
            ((uint4*)bins)[i] = sv;
        if (threadIdx.x < HNODES) hcnt[threadIdx.x] = 0;
    }
    __syncthreads();

    const int cb = blockIdx.x >> 1;            // coarse bucket 0..390
    const unsigned hf = blockIdx.x & 1u;       // 128-node half
    const int cnt = min(gcnt[cb * GSTRIDE], CAPB);
    const unsigned* bp = buf + (size_t)cb * CAPB;

    // filtered single-pass scatter into per-node bins (pre-masked entries)
    {
        int nv = cnt & ~3;
        for (int i = threadIdx.x * 4; i < nv; i += 2048) {
            uint4 e4 = *(const uint4*)(bp + i);
#pragma unroll
            for (int u = 0; u < 4; ++u) {
                unsigned e = (u == 0) ? e4.x : (u == 1) ? e4.y : (u == 2) ? e4.z : e4.w;
                if ((e >> 31) == hf) {
                    int ln = (e >> 24) & 127;
                    int p = atomicAdd(&hcnt[ln], 1);
                    if (p < SLOT) bins[ln * SLOT + p] = e & 0xFFFFFFu;
                }
            }
        }
        for (int i = nv + threadIdx.x; i < cnt; i += 512) {
            unsigned e = bp[i];
            if ((e >> 31) == hf) {
                int ln = (e >> 24) & 127;
                int p = atomicAdd(&hcnt[ln], 1);
                if (p < SLOT) bins[ln * SLOT + p] = e & 0xFFFFFFu;
            }
        }
    }
    __syncthreads();

    // branch-free rank by count (desc): balanced wave assignment
    if (threadIdx.x < HNODES) {
        int c = hcnt[threadIdx.x];
        int r = 0;
#pragma unroll 8
        for (int j = 0; j < HNODES; ++j) {
            int cj = hcnt[j];
            r += (cj > c) || (cj == c && j < (int)threadIdx.x);
        }
        perm[r] = threadIdx.x;
    }
    __syncthreads();

    const int lane16 = threadIdx.x & 15;   // channel pair index (ch 2l,2l+1)
    const int qw = threadIdx.x >> 4;       // 16-lane group 0..31
    const int wvg = qw >> 2, qi = qw & 3;  // wave id 0..7, quarter in wave
    const float bl2 = beta[0] * 1.4426950408889634f;   // beta * log2(e)
    const unsigned loff = (unsigned)lane16 * 4u;       // channel-pair byte off
    const char* mb = (const char*)msgb;                // saddr base

    // dword dual-stream gather + entry prefetch: 2 nodes/group, 8 dwords
    // in flight; entries[t+1] ds_read issued under t's global loads.
#pragma unroll
    for (int kp = 0; kp < 2; ++kp) {
        int window = kp ? (15 - wvg) : wvg;
        int s = window * 8 + qi * 2;
        int na = perm[s], nc = perm[s + 1];
        int ma = min(hcnt[na], SLOT);
        int mc = min(hcnt[nc], SLOT);
        int T = max((ma + 3) >> 2, (mc + 3) >> 2);
        const uint4* ba = (const uint4*)&bins[na * SLOT];
        const uint4* bc = (const uint4*)&bins[nc * SLOT];
        float seaL = 0.f, seaH = 0.f, smaL = 0.f, smaH = 0.f;
        float secL = 0.f, secH = 0.f, smcL = 0.f, smcH = 0.f;
        uint4 ea = ba[0];
        uint4 ec = bc[0];
        for (int t = 0; t < T; ++t) {
            unsigned da0 = *(const unsigned*)(mb + (ea.x + loff));
            unsigned da1 = *(const unsigned*)(mb + (ea.y + loff));
            unsigned da2 = *(const unsigned*)(mb + (ea.z + loff));
            unsigned da3 = *(const unsigned*)(mb + (ea.w + loff));
            unsigned dc0 = *(const unsigned*)(mb + (ec.x + loff));
            unsigned dc1 = *(const unsigned*)(mb + (ec.y + loff));
            unsigned dc2 = *(const unsigned*)(mb + (ec.z + loff));
            unsigned dc3 = *(const unsigned*)(mb + (ec.w + loff));
            uint4 ean = ba[t + 1];                 // prefetch next entries
            uint4 ecn = bc[t + 1];                 // (16B slack covers t=T-1)
            // lo channel = bits 0-15, hi channel = bits 16-31
            float aL0 = __uint_as_float(da0 << 16), aH0 = __uint_as_float(da0 & 0xFFFF0000u);
            float aL1 = __uint_as_float(da1 << 16), aH1 = __uint_as_float(da1 & 0xFFFF0000u);
            float aL2 = __uint_as_float(da2 << 16), aH2 = __uint_as_float(da2 & 0xFFFF0000u);
            float aL3 = __uint_as_float(da3 << 16), aH3 = __uint_as_float(da3 & 0xFFFF0000u);
            float cL0 = __uint_as_float(dc0 << 16), cH0 = __uint_as_float(dc0 & 0xFFFF0000u);
            float cL1 = __uint_as_float(dc1 << 16), cH1 = __uint_as_float(dc1 & 0xFFFF0000u);
            float cL2 = __uint_as_float(dc2 << 16), cH2 = __uint_as_float(dc2 & 0xFFFF0000u);
            float cL3 = __uint_as_float(dc3 << 16), cH3 = __uint_as_float(dc3 & 0xFFFF0000u);
            float wL0 = __builtin_amdgcn_exp2f(bl2 * aL0);
            float wL1 = __builtin_amdgcn_exp2f(bl2 * aL1);
            float wL2 = __builtin_amdgcn_exp2f(bl2 * aL2);
            float wL3 = __builtin_amdgcn_exp2f(bl2 * aL3);
            float wH0 = __builtin_amdgcn_exp2f(bl2 * aH0);
            float wH1 = __builtin_amdgcn_exp2f(bl2 * aH1);
            float wH2 = __builtin_amdgcn_exp2f(bl2 * aH2);
            float wH3 = __builtin_amdgcn_exp2f(bl2 * aH3);
            float vL0 = __builtin_amdgcn_exp2f(bl2 * cL0);
            float vL1 = __builtin_amdgcn_exp2f(bl2 * cL1);
            float vL2 = __builtin_amdgcn_exp2f(bl2 * cL2);
            float vL3 = __builtin_amdgcn_exp2f(bl2 * cL3);
            float vH0 = __builtin_amdgcn_exp2f(bl2 * cH0);
            float vH1 = __builtin_amdgcn_exp2f(bl2 * cH1);
            float vH2 = __builtin_amdgcn_exp2f(bl2 * cH2);
            float vH3 = __builtin_amdgcn_exp2f(bl2 * cH3);
            seaL += (wL0 + wL1) + (wL2 + wL3);
            seaH += (wH0 + wH1) + (wH2 + wH3);
            secL += (vL0 + vL1) + (vL2 + vL3);
            secH += (vH0 + vH1) + (vH2 + vH3);
            smaL += wL0 * aL0 + wL1 * aL1 + wL2 * aL2 + wL3 * aL3;
            smaH += wH0 * aH0 + wH1 * aH1 + wH2 * aH2 + wH3 * aH3;
            smcL += vL0 * cL0 + vL1 * cL1 + vL2 * cL2 + vL3 * cL3;
            smcH += vH0 * cH0 + vH1 * cH1 + vH2 * cH2 + vH3 * cH3;
            ea = ean;
            ec = ecn;
        }
        float haL = (seaL > 0.0f) ? (smaL / seaL) : 0.0f;
        float haH = (seaH > 0.0f) ? (smaH / seaH) : 0.0f;
        float hcL = (secL > 0.0f) ? (smcL / secL) : 0.0f;
        float hcH = (secH > 0.0f) ? (smcH / secH) : 0.0f;
        // packed ushort2 writes (byte offset node*80 + lane16*4, 4B aligned)
        *(unsigned*)&sha[na * 40 + lane16 * 2] =
            (unsigned)f2b(haL) | ((unsigned)f2b(haH) << 16);
        *(unsigned*)&sha[nc * 40 + lane16 * 2] =
            (unsigned)f2b(hcL) | ((unsigned)f2b(hcH) << 16);
    }
    __syncthreads();   // bins dead from here; pool reused as hid

    // ---- MFMA MLP: wave wv owns nodes [blockIdx.x*128 + wv*16, +16) ----
    const int wv = threadIdx.x >> 6;       // 0..7
    const int lane = threadIdx.x & 63;
    const int col = lane & 15, quad = lane >> 4;
    const int n0 = blockIdx.x * HNODES + wv * 16;

    bf16x8 a = *(const bf16x8*)&sha[(wv * 16 + col) * 40 + quad * 8];

    const bf16x8* w1p = (const bf16x8*)W1f;
    f32x4 z = {0.f, 0.f, 0.f, 0.f};
    f32x4 c0 = __builtin_amdgcn_mfma_f32_16x16x32_bf16(a, w1p[0 * 64 + lane], z, 0, 0, 0);
    f32x4 c1 = __builtin_amdgcn_mfma_f32_16x16x32_bf16(a, w1p[1 * 64 + lane], z, 0, 0, 0);
    f32x4 c2 = __builtin_amdgcn_mfma_f32_16x16x32_bf16(a, w1p[2 * 64 + lane], z, 0, 0, 0);
    f32x4 c3 = __builtin_amdgcn_mfma_f32_16x16x32_bf16(a, w1p[3 * 64 + lane], z, 0, 0, 0);

    float bb0 = b1[col], bb1 = b1[16 + col], bb2 = b1[32 + col], bb3 = b1[48 + col];
    unsigned short* hrow = &hid[wv * 16 * 72];
#pragma unroll
    for (int r = 0; r < 4; ++r) {
        int row = quad * 4 + r;
        hrow[row * 72 + col]      = f2b(fmaxf(c0[r] + bb0, 0.f));
        hrow[row * 72 + 16 + col] = f2b(fmaxf(c1[r] + bb1, 0.f));
        hrow[row * 72 + 32 + col] = f2b(fmaxf(c2[r] + bb2, 0.f));
        hrow[row * 72 + 48 + col] = f2b(fmaxf(c3[r] + bb3, 0.f));
    }
    // per-wave LDS region: in-wave ordering suffices (r7-r17 precedent)

    bf16x8 h0 = *(const bf16x8*)&hrow[col * 72 + quad * 8];        // k 0..31
    bf16x8 h1 = *(const bf16x8*)&hrow[col * 72 + 32 + quad * 8];   // k 32..63

    const bf16x8* w2p = (const bf16x8*)W2f;
    f32x4 o0 = __builtin_amdgcn_mfma_f32_16x16x32_bf16(h0, w2p[0 * 64 + lane], z, 0, 0, 0);
    o0 = __builtin_amdgcn_mfma_f32_16x16x32_bf16(h1, w2p[1 * 64 + lane], o0, 0, 0, 0);
    f32x4 o1 = __builtin_amdgcn_mfma_f32_16x16x32_bf16(h0, w2p[2 * 64 + lane], z, 0, 0, 0);
    o1 = __builtin_amdgcn_mfma_f32_16x16x32_bf16(h1, w2p[3 * 64 + lane], o1, 0, 0, 0);

    float d0 = b2[col], d1 = b2[16 + col];
#pragma unroll
    for (int r = 0; r < 4; ++r) {
        int row = n0 + quad * 4 + r;
        if (row < N_NODES) {
            out[(size_t)row * DCH + col]      = o0[r] + d0;
            out[(size_t)row * DCH + 16 + col] = o1[r] + d1;
        }
    }
}

extern "C" void kernel_launch(void* const* d_in, const int* in_sizes, int n_in,
                              void* d_out, int out_size, void* d_ws, size_t ws_size,
                              hipStream_t stream) {
    const float* x    = (const float*)d_in[0];
    const int*   eidx = (const int*)d_in[1];
    const float* beta = (const float*)d_in[2];
    const float* W1   = (const float*)d_in[3];
    const float* b1   = (const float*)d_in[4];
    const float* W2   = (const float*)d_in[5];
    const float* b2   = (const float*)d_in[6];
    float* out = (float*)d_out;

    int* gcnt = (int*)d_ws;                                        // 25 KB
    unsigned* buf = (unsigned*)(gcnt + NB * GSTRIDE);              // 7.1 MB
    unsigned short* msgb = (unsigned short*)(buf + (size_t)NB * CAPB); // 6.4 MB + sentinel
    unsigned short* W1f = msgb + (size_t)(N_NODES + 1) * DCH;      // 4 KB
    unsigned short* W2f = W1f + 4 * 64 * 8;                        // 4 KB

    hipMemsetAsync(gcnt, 0, (size_t)NB * GSTRIDE * sizeof(int), stream);

    genconv_partition<<<P1_BLOCKS, P1_THREADS, 0, stream>>>(
        x, eidx, W1, W2, gcnt, buf, msgb, W1f, W2f);
    genconv_agg_mlp<<<2 * NB, 512, 0, stream>>>(msgb, gcnt, buf, beta,
                                                W1f, W2f, b1, b2, out);
}